// Round 6
// baseline (331.449 us; speedup 1.0000x reference)
//
#include <hip/hip_runtime.h>
#include <math.h>

constexpr int HID  = 2048;
constexpr int NEXP = 128;
constexpr int TOPK = 8;
constexpr int BM   = 32;
constexpr int BK   = 32;
constexpr int ROWS = 16384;

constexpr int AS_STRIDE = BM + 4;    // 36 floats: rows 16B-aligned, write conflicts benign
constexpr int BS_STRIDE = NEXP + 4;  // 132 floats: rows 16B-aligned, write conflicts 2-way (free)

__global__ __launch_bounds__(256, 2)
void router_kernel(const float* __restrict__ X, const float* __restrict__ W,
                   float* __restrict__ out_w, float* __restrict__ out_i,
                   float* __restrict__ out_l)
{
    __shared__ float As[BK][AS_STRIDE];   // transposed A: As[k][m]
    __shared__ float Bs[BK][BS_STRIDE];   // transposed W: Bs[k][e]; reused for logit staging

    const int tid = threadIdx.x;
    const int tx  = tid & 31;   // col group: cols tx*4 .. tx*4+3
    const int ty  = tid >> 5;   // row group: rows ty*4 .. ty*4+3
    const int row0 = blockIdx.x * BM;

    // A staging: 32 rows x 32 k per iter; 8 threads/row, one float4 each
    const int a_row = tid >> 3;
    const int a_kq  = (tid & 7) << 2;
    // B staging: 128 experts x 32 k per iter; 2 threads/expert, 16 k-floats each
    const int b_e = tid >> 1;
    const int b_k = (tid & 1) << 4;

    const float* __restrict__ Xp = X + (size_t)(row0 + a_row) * HID + a_kq;
    const float* __restrict__ Wp = W + (size_t)b_e * HID + b_k;

    float acc[4][4] = {};

    for (int k0 = 0; k0 < HID; k0 += BK) {
        const float4 av  = *reinterpret_cast<const float4*>(Xp + k0);
        const float4 bv0 = *reinterpret_cast<const float4*>(Wp + k0 + 0);
        const float4 bv1 = *reinterpret_cast<const float4*>(Wp + k0 + 4);
        const float4 bv2 = *reinterpret_cast<const float4*>(Wp + k0 + 8);
        const float4 bv3 = *reinterpret_cast<const float4*>(Wp + k0 + 12);

        __syncthreads();   // previous iter's compute done before overwriting LDS

        As[a_kq + 0][a_row] = av.x;
        As[a_kq + 1][a_row] = av.y;
        As[a_kq + 2][a_row] = av.z;
        As[a_kq + 3][a_row] = av.w;

        Bs[b_k +  0][b_e] = bv0.x;
        Bs[b_k +  1][b_e] = bv0.y;
        Bs[b_k +  2][b_e] = bv0.z;
        Bs[b_k +  3][b_e] = bv0.w;
        Bs[b_k +  4][b_e] = bv1.x;
        Bs[b_k +  5][b_e] = bv1.y;
        Bs[b_k +  6][b_e] = bv1.z;
        Bs[b_k +  7][b_e] = bv1.w;
        Bs[b_k +  8][b_e] = bv2.x;
        Bs[b_k +  9][b_e] = bv2.y;
        Bs[b_k + 10][b_e] = bv2.z;
        Bs[b_k + 11][b_e] = bv2.w;
        Bs[b_k + 12][b_e] = bv3.x;
        Bs[b_k + 13][b_e] = bv3.y;
        Bs[b_k + 14][b_e] = bv3.z;
        Bs[b_k + 15][b_e] = bv3.w;

        __syncthreads();

        #pragma unroll 8
        for (int kk = 0; kk < BK; ++kk) {
            const float4 a4 = *reinterpret_cast<const float4*>(&As[kk][ty << 2]);
            const float4 b4 = *reinterpret_cast<const float4*>(&Bs[kk][tx << 2]);
            const float ar[4] = {a4.x, a4.y, a4.z, a4.w};
            const float br[4] = {b4.x, b4.y, b4.z, b4.w};
            #pragma unroll
            for (int r = 0; r < 4; ++r)
                #pragma unroll
                for (int c = 0; c < 4; ++c)
                    acc[r][c] = fmaf(ar[r], br[c], acc[r][c]);
        }
    }

    // Epilogue: write logits to global, stage them in LDS (reuse Bs: 32 rows x 128 cols)
    __syncthreads();
    #pragma unroll
    for (int r = 0; r < 4; ++r) {
        const int lrow = (ty << 2) + r;
        const float4 v = make_float4(acc[r][0], acc[r][1], acc[r][2], acc[r][3]);
        *reinterpret_cast<float4*>(&Bs[lrow][tx << 2]) = v;
        *reinterpret_cast<float4*>(&out_l[(size_t)(row0 + lrow) * NEXP + (tx << 2)]) = v;
    }
    __syncthreads();

    // Top-8 + renormalized softmax weights: one lane per row (rows 0..31)
    if (tid < BM) {
        float v[TOPK];
        int   ix[TOPK];
        #pragma unroll
        for (int j = 0; j < TOPK; ++j) { v[j] = -INFINITY; ix[j] = 0; }

        for (int e = 0; e < NEXP; ++e) {
            const float s = Bs[tid][e];
            if (s > v[TOPK - 1]) {          // strict >: ties keep the earlier (lower) index
                v[TOPK - 1] = s; ix[TOPK - 1] = e;
                #pragma unroll
                for (int j = TOPK - 1; j > 0; --j) {
                    if (v[j] > v[j - 1]) {  // strict >: stable for ties
                        const float tv = v[j]; v[j] = v[j - 1]; v[j - 1] = tv;
                        const int   ti = ix[j]; ix[j] = ix[j - 1]; ix[j - 1] = ti;
                    }
                }
            }
        }

        // normalized weights = exp(v - m) / sum_top8 exp(v - m)  (full softmax Z cancels)
        const float m = v[0];
        float ex[TOPK];
        float sum = 0.f;
        #pragma unroll
        for (int j = 0; j < TOPK; ++j) { ex[j] = expf(v[j] - m); sum += ex[j]; }

        const size_t grow = (size_t)(row0 + tid);
        #pragma unroll
        for (int j = 0; j < TOPK; ++j) {
            out_w[grow * TOPK + j] = ex[j] / sum;
            out_i[grow * TOPK + j] = (float)ix[j];   // whole d_out is read back as f32
        }
    }
}

extern "C" void kernel_launch(void* const* d_in, const int* in_sizes, int n_in,
                              void* d_out, int out_size, void* d_ws, size_t ws_size,
                              hipStream_t stream) {
    const float* X = (const float*)d_in[0];
    const float* W = (const float*)d_in[1];
    float* out   = (float*)d_out;
    float* out_w = out;                                  // [16384, 8]
    float* out_i = out + (size_t)ROWS * TOPK;            // [16384, 8] (indices as float)
    float* out_l = out + (size_t)ROWS * TOPK * 2;        // [16384, 128]

    dim3 grid(ROWS / BM);
    router_kernel<<<grid, 256, 0, stream>>>(X, W, out_w, out_i, out_l);
}